// Round 1
// baseline (525.567 us; speedup 1.0000x reference)
//
#include <hip/hip_runtime.h>

// VQ nearest-embedding: x (32,256,32,32) f32, emb (256,2048) f32.
// argmin_k ||x_n - e_k||^2 == argmin_k (0.5*||e_k||^2 - x_n . e_k)  -> gather e_{k*}.
// Compute-bound fp32: 17.2 G MACs, vector-ALU floor ~219 us.

#define DD 256      // latent dim
#define KK 2048     // codebook size
#define SS 1024     // H*W
#define BB 32
#define NN (BB * SS)  // 32768 latents

#define MT 128      // latents per block
#define KT 256      // codes per K-tile
#define DT 16       // D-chunk staged in LDS
#define NTHREADS 512

// Kernel 1: hn[k] = 0.5 * sum_d emb[d][k]^2   (coalesced along k)
__global__ __launch_bounds__(256) void hn_kernel(const float* __restrict__ emb,
                                                 float* __restrict__ hn) {
    int k = blockIdx.x * 256 + threadIdx.x;
    float a = 0.f;
#pragma unroll 8
    for (int d = 0; d < DD; ++d) {
        float e = emb[d * KK + k];
        a += e * e;
    }
    hn[k] = 0.5f * a;
}

// Kernel 2: per block: 128 latents vs all 2048 codes, fused argmin + gather.
__global__ __launch_bounds__(NTHREADS) void vq_kernel(
        const float* __restrict__ x, const float* __restrict__ emb,
        const float* __restrict__ hn, float* __restrict__ out) {
    __shared__ float xs[DT][MT];   // x^T tile: xs[d][m]
    __shared__ float es[DT][KT];   // emb tile: es[d][k]
    __shared__ int bks[MT];        // best code per latent

    const int tid = threadIdx.x;
    const int tx = tid & 31;   // k-direction: 32 groups of 8 codes
    const int ty = tid >> 5;   // m-direction: 16 groups of 8 latents
    const int base_n = blockIdx.x * MT;
    const int bq = base_n >> 10;        // batch index (SS = 1024)
    const int sb = base_n & (SS - 1);   // spatial base (multiple of 128)

    float bestv[8];
    int bestk[8];
#pragma unroll
    for (int i = 0; i < 8; ++i) { bestv[i] = 3.4e38f; bestk[i] = 0; }

    for (int kt = 0; kt < KK; kt += KT) {
        float acc[8][8];
#pragma unroll
        for (int i = 0; i < 8; ++i)
#pragma unroll
            for (int j = 0; j < 8; ++j) acc[i][j] = 0.f;

        for (int dt = 0; dt < DD; dt += DT) {
            __syncthreads();  // protect LDS before rewrite (covers prev readers)
            // stage xs: DT*MT/4 = 512 float4, one per thread
            {
                int d = tid >> 5;   // 0..15
                int c = tid & 31;   // float4 column
                const float4* src = reinterpret_cast<const float4*>(
                        &x[(bq * DD + dt + d) * SS + sb]);
                reinterpret_cast<float4*>(&xs[d][0])[c] = src[c];
            }
            // stage es: DT*KT/4 = 1024 float4, two per thread
#pragma unroll
            for (int r = 0; r < 2; ++r) {
                int v = r * NTHREADS + tid;
                int d = v >> 6;     // 0..15
                int c = v & 63;
                const float4* src = reinterpret_cast<const float4*>(
                        &emb[(dt + d) * KK + kt]);
                reinterpret_cast<float4*>(&es[d][0])[c] = src[c];
            }
            __syncthreads();
#pragma unroll
            for (int d = 0; d < DT; ++d) {
                float4 a0 = reinterpret_cast<float4*>(&xs[d][0])[ty * 2];
                float4 a1 = reinterpret_cast<float4*>(&xs[d][0])[ty * 2 + 1];
                float4 b0 = reinterpret_cast<float4*>(&es[d][0])[tx * 2];
                float4 b1 = reinterpret_cast<float4*>(&es[d][0])[tx * 2 + 1];
                float av[8] = {a0.x, a0.y, a0.z, a0.w, a1.x, a1.y, a1.z, a1.w};
                float bv[8] = {b0.x, b0.y, b0.z, b0.w, b1.x, b1.y, b1.z, b1.w};
#pragma unroll
                for (int i = 0; i < 8; ++i)
#pragma unroll
                    for (int j = 0; j < 8; ++j)
                        acc[i][j] += av[i] * bv[j];
            }
        }
        // epilogue for this K-tile: cost c = hn - dot; running argmin
        const float4* hp = reinterpret_cast<const float4*>(&hn[kt + tx * 8]);
        float4 h0 = hp[0], h1 = hp[1];
        float hv[8] = {h0.x, h0.y, h0.z, h0.w, h1.x, h1.y, h1.z, h1.w};
#pragma unroll
        for (int i = 0; i < 8; ++i) {
            float v = hv[0] - acc[i][0];
            int kb = kt + tx * 8;
#pragma unroll
            for (int j = 1; j < 8; ++j) {
                float c = hv[j] - acc[i][j];
                if (c < v) { v = c; kb = kt + tx * 8 + j; }  // strict <: first idx wins
            }
            // butterfly argmin across the 32-lane tx group (tie -> smaller k)
#pragma unroll
            for (int md = 1; md < 32; md <<= 1) {
                float ov = __shfl_xor(v, md);
                int ok = __shfl_xor(kb, md);
                if (ov < v || (ov == v && ok < kb)) { v = ov; kb = ok; }
            }
            if (v < bestv[i]) { bestv[i] = v; bestk[i] = kb; }
            // tie vs earlier kt: earlier has smaller k, strict < keeps it
        }
    }
    if (tx == 0) {
#pragma unroll
        for (int i = 0; i < 8; ++i) bks[ty * 8 + i] = bestk[i];
    }
    __syncthreads();
    // gather: out[(bq*DD + d)*SS + sb + m] = emb[d*KK + bks[m]]
    {
        int mq = tid & 31;   // float4 group along m (m = mq*4 .. mq*4+3)
        int dg = tid >> 5;   // 0..15, each covers 16 d rows
        int k0 = bks[mq * 4 + 0];
        int k1 = bks[mq * 4 + 1];
        int k2 = bks[mq * 4 + 2];
        int k3 = bks[mq * 4 + 3];
#pragma unroll 4
        for (int dd = 0; dd < 16; ++dd) {
            int d = dg * 16 + dd;
            const float* er = emb + d * KK;
            float4 o;
            o.x = er[k0]; o.y = er[k1]; o.z = er[k2]; o.w = er[k3];
            reinterpret_cast<float4*>(&out[(bq * DD + d) * SS + sb])[mq] = o;
        }
    }
}

extern "C" void kernel_launch(void* const* d_in, const int* in_sizes, int n_in,
                              void* d_out, int out_size, void* d_ws, size_t ws_size,
                              hipStream_t stream) {
    const float* x = (const float*)d_in[0];     // (32,256,32,32)
    const float* emb = (const float*)d_in[1];   // (256,2048)
    float* out = (float*)d_out;                 // (32,256,32,32)
    float* hn = (float*)d_ws;                   // 2048 floats of scratch

    hipLaunchKernelGGL(hn_kernel, dim3(KK / 256), dim3(256), 0, stream, emb, hn);
    hipLaunchKernelGGL(vq_kernel, dim3(NN / MT), dim3(NTHREADS), 0, stream,
                       x, emb, hn, out);
}

// Round 3
// 300.557 us; speedup vs baseline: 1.7486x; 1.7486x over previous
//
#include <hip/hip_runtime.h>

// VQ nearest-embedding, fused single-kernel split-bf16 MFMA.
// argmin_k ||x-e_k||^2 == argmin_k (0.5*||e_k||^2 - x.e_k).
// x = xh+xl, e = eh+el (bf16 RNE splits); 4 MFMA cross terms (validated round 2).
// No atomics / no big workspace: only 8 KB of d_ws for 0.5*||e||^2 (proven safe).

typedef __attribute__((ext_vector_type(8))) short short8v;   // 8 bf16 = 4 VGPRs
typedef __attribute__((ext_vector_type(16))) float floatx16; // 32x32 acc
typedef unsigned int uint;
typedef unsigned short ushort;

#define DD 256
#define KK 2048
#define SS 1024
#define NN 32768
#define MT 128      // latents per block
#define NTT 256     // codes per kt tile (block covers all 2048 in 8 tiles)
#define DC 16       // K-depth per chunk (one 32x32x16 step)
#define LDA 24      // LDS row stride in bf16: 48 B -> 16B-aligned, banks spread
#define MFMA_BF16 __builtin_amdgcn_mfma_f32_32x32x16_bf16

__device__ __forceinline__ ushort f2bf(float f) {   // fp32 -> bf16 RNE
    uint b = __float_as_uint(f);
    return (ushort)((b + 0x7FFFu + ((b >> 16) & 1u)) >> 16);
}

__global__ __launch_bounds__(256) void hn_kernel(const float* __restrict__ emb,
                                                 float* __restrict__ hn) {
    int k = blockIdx.x * 256 + threadIdx.x;
    float a = 0.f;
#pragma unroll 8
    for (int d = 0; d < DD; ++d) { float e = emb[d * KK + k]; a += e * e; }
    hn[k] = 0.5f * a;
}

__global__ __launch_bounds__(512, 2) void vq_fused(
        const float* __restrict__ x, const float* __restrict__ emb,
        const float* __restrict__ hn, float* __restrict__ out) {
    __shared__ ushort Ah[MT * LDA], Al[MT * LDA];
    __shared__ ushort Bh[NTT * LDA], Bl[NTT * LDA];
    __shared__ float sv[4][MT];
    __shared__ int   sc[4][MT];
    __shared__ int   bc[MT];

    const int tid = threadIdx.x;
    const int lane = tid & 63;
    const int wid = tid >> 6;          // 8 waves: 2(m) x 4(n)
    const int colk = lane & 31;
    const int half = lane >> 5;
    const int wm = (wid & 1) * 64;     // wave tile 64(m) x 64(n)
    const int wn = (wid >> 1) * 64;

    const int base_n = blockIdx.x * MT;
    const int bq = base_n >> 10;          // batch (SS = 1024)
    const int sb = base_n & (SS - 1);     // spatial base

    // staging assignment
    const int lat_a = tid & 127;          // A: one latent, 4 d's
    const int dqa = (tid >> 7) * 4;
    const int cod_b = tid & 255;          // B: one code, 8 d's
    const int dqb = (tid >> 8) * 8;

    const float* xb = x + ((size_t)bq * DD + dqa) * SS + sb + lat_a;

    floatx16 acc[2][2];
#pragma unroll
    for (int i = 0; i < 2; ++i)
#pragma unroll
        for (int j = 0; j < 2; ++j) acc[i][j] = (floatx16)(0.0f);

    float bestv[2][16];
    int bestc[2][16];
#pragma unroll
    for (int t = 0; t < 2; ++t)
#pragma unroll
        for (int r = 0; r < 16; ++r) { bestv[t][r] = 3.4e38f; bestc[t][r] = 0; }

    // prefetch registers (chunk 0: kt=0, dt=0)
    float fa[4], fb[8];
#pragma unroll
    for (int i = 0; i < 4; ++i) fa[i] = xb[(size_t)i * SS];
    {
        const float* p = emb + (size_t)dqb * KK + cod_b;
#pragma unroll
        for (int i = 0; i < 8; ++i) fb[i] = p[(size_t)i * KK];
    }

    for (int c = 0; c < 128; ++c) {          // 8 kt x 16 dt chunks
        const int kt = c >> 4;
        if (c) __syncthreads();              // prev chunk's LDS readers done
        // ---- convert fa/fb -> split bf16, write LDS ----
        {
            ushort h[4], l[4];
#pragma unroll
            for (int i = 0; i < 4; ++i) {
                h[i] = f2bf(fa[i]);
                float r = fa[i] - __uint_as_float((uint)h[i] << 16);
                l[i] = f2bf(r);
            }
            uint2 hw, lw;
            hw.x = (uint)h[0] | ((uint)h[1] << 16);
            hw.y = (uint)h[2] | ((uint)h[3] << 16);
            lw.x = (uint)l[0] | ((uint)l[1] << 16);
            lw.y = (uint)l[2] | ((uint)l[3] << 16);
            *reinterpret_cast<uint2*>(&Ah[lat_a * LDA + dqa]) = hw;
            *reinterpret_cast<uint2*>(&Al[lat_a * LDA + dqa]) = lw;

            ushort g[8], m[8];
#pragma unroll
            for (int i = 0; i < 8; ++i) {
                g[i] = f2bf(fb[i]);
                float r = fb[i] - __uint_as_float((uint)g[i] << 16);
                m[i] = f2bf(r);
            }
            uint4 gh, gl;
            gh.x = (uint)g[0] | ((uint)g[1] << 16);
            gh.y = (uint)g[2] | ((uint)g[3] << 16);
            gh.z = (uint)g[4] | ((uint)g[5] << 16);
            gh.w = (uint)g[6] | ((uint)g[7] << 16);
            gl.x = (uint)m[0] | ((uint)m[1] << 16);
            gl.y = (uint)m[2] | ((uint)m[3] << 16);
            gl.z = (uint)m[4] | ((uint)m[5] << 16);
            gl.w = (uint)m[6] | ((uint)m[7] << 16);
            *reinterpret_cast<uint4*>(&Bh[cod_b * LDA + dqb]) = gh;
            *reinterpret_cast<uint4*>(&Bl[cod_b * LDA + dqb]) = gl;
        }
        __syncthreads();
        // ---- prefetch next chunk's globals (in flight during MFMA) ----
        if (c < 127) {
            const int c1 = c + 1;
            const int kt1 = c1 >> 4;
            const int dt1 = (c1 & 15) * DC;
#pragma unroll
            for (int i = 0; i < 4; ++i) fa[i] = xb[(size_t)(dt1 + i) * SS];
            const float* p = emb + (size_t)(dt1 + dqb) * KK + kt1 * NTT + cod_b;
#pragma unroll
            for (int i = 0; i < 8; ++i) fb[i] = p[(size_t)i * KK];
        }
        // ---- fragments + 16 MFMA (4 split terms x 2x2 tiles) ----
        const int fo = colk * LDA + half * 8;
        short8v ah0 = *reinterpret_cast<const short8v*>(&Ah[fo + wm * LDA]);
        short8v ah1 = *reinterpret_cast<const short8v*>(&Ah[fo + (wm + 32) * LDA]);
        short8v al0 = *reinterpret_cast<const short8v*>(&Al[fo + wm * LDA]);
        short8v al1 = *reinterpret_cast<const short8v*>(&Al[fo + (wm + 32) * LDA]);
        short8v bh0 = *reinterpret_cast<const short8v*>(&Bh[fo + wn * LDA]);
        short8v bh1 = *reinterpret_cast<const short8v*>(&Bh[fo + (wn + 32) * LDA]);
        short8v bl0 = *reinterpret_cast<const short8v*>(&Bl[fo + wn * LDA]);
        short8v bl1 = *reinterpret_cast<const short8v*>(&Bl[fo + (wn + 32) * LDA]);

        acc[0][0] = MFMA_BF16(ah0, bh0, acc[0][0], 0, 0, 0);
        acc[0][0] = MFMA_BF16(ah0, bl0, acc[0][0], 0, 0, 0);
        acc[0][0] = MFMA_BF16(al0, bh0, acc[0][0], 0, 0, 0);
        acc[0][0] = MFMA_BF16(al0, bl0, acc[0][0], 0, 0, 0);

        acc[0][1] = MFMA_BF16(ah0, bh1, acc[0][1], 0, 0, 0);
        acc[0][1] = MFMA_BF16(ah0, bl1, acc[0][1], 0, 0, 0);
        acc[0][1] = MFMA_BF16(al0, bh1, acc[0][1], 0, 0, 0);
        acc[0][1] = MFMA_BF16(al0, bl1, acc[0][1], 0, 0, 0);

        acc[1][0] = MFMA_BF16(ah1, bh0, acc[1][0], 0, 0, 0);
        acc[1][0] = MFMA_BF16(ah1, bl0, acc[1][0], 0, 0, 0);
        acc[1][0] = MFMA_BF16(al1, bh0, acc[1][0], 0, 0, 0);
        acc[1][0] = MFMA_BF16(al1, bl0, acc[1][0], 0, 0, 0);

        acc[1][1] = MFMA_BF16(ah1, bh1, acc[1][1], 0, 0, 0);
        acc[1][1] = MFMA_BF16(ah1, bl1, acc[1][1], 0, 0, 0);
        acc[1][1] = MFMA_BF16(al1, bh1, acc[1][1], 0, 0, 0);
        acc[1][1] = MFMA_BF16(al1, bl1, acc[1][1], 0, 0, 0);

        // ---- per-kt epilogue: scores -> running argmin, reset acc ----
        if ((c & 15) == 15) {
            const int cd0 = kt * NTT + wn + colk;
            const int cd1 = cd0 + 32;
            const float h0 = hn[cd0];
            const float h1 = hn[cd1];
#pragma unroll
            for (int tm = 0; tm < 2; ++tm) {
#pragma unroll
                for (int r = 0; r < 16; ++r) {
                    float s0 = h0 - acc[tm][0][r];
                    float s1 = h1 - acc[tm][1][r];
                    float v = s0; int cd = cd0;
                    if (s1 < s0) { v = s1; cd = cd1; }   // strict: smaller code wins ties
                    if (v < bestv[tm][r]) { bestv[tm][r] = v; bestc[tm][r] = cd; }
                    acc[tm][0][r] = 0.f;
                    acc[tm][1][r] = 0.f;
                }
            }
        }
    }

    // ---- cross-lane argmin: butterfly over the 32 colk lanes ----
#pragma unroll
    for (int tm = 0; tm < 2; ++tm) {
#pragma unroll
        for (int r = 0; r < 16; ++r) {
            float v = bestv[tm][r];
            int cd = bestc[tm][r];
#pragma unroll
            for (int mk = 1; mk < 32; mk <<= 1) {
                float ov = __shfl_xor(v, mk);
                int oc = __shfl_xor(cd, mk);
                if (ov < v || (ov == v && oc < cd)) { v = ov; cd = oc; }
            }
            if (colk == 0) {
                const int row = (r & 3) + 8 * (r >> 2) + 4 * half;  // verified C/D map
                sv[wid >> 1][wm + tm * 32 + row] = v;
                sc[wid >> 1][wm + tm * 32 + row] = cd;
            }
        }
    }
    __syncthreads();
    // ---- combine the 4 n-wave groups ----
    if (tid < MT) {
        float v = sv[0][tid]; int cd = sc[0][tid];
#pragma unroll
        for (int g = 1; g < 4; ++g) {
            float ov = sv[g][tid]; int oc = sc[g][tid];
            if (ov < v || (ov == v && oc < cd)) { v = ov; cd = oc; }
        }
        bc[tid] = cd;
    }
    __syncthreads();
    // ---- fused gather: out[(bq*DD+d)*SS + sb + m] = emb[d*KK + bc[m]] ----
    {
        const int mq = tid & 31;     // float4 group along m
        const int dg = tid >> 5;     // 0..15, 16 d's each
        const int k0 = bc[mq * 4 + 0];
        const int k1 = bc[mq * 4 + 1];
        const int k2 = bc[mq * 4 + 2];
        const int k3 = bc[mq * 4 + 3];
#pragma unroll 4
        for (int dd = 0; dd < 16; ++dd) {
            const int d = dg * 16 + dd;
            const float* er = emb + (size_t)d * KK;
            float4 o = make_float4(er[k0], er[k1], er[k2], er[k3]);
            reinterpret_cast<float4*>(&out[((size_t)bq * DD + d) * SS + sb])[mq] = o;
        }
    }
}

extern "C" void kernel_launch(void* const* d_in, const int* in_sizes, int n_in,
                              void* d_out, int out_size, void* d_ws, size_t ws_size,
                              hipStream_t stream) {
    const float* x = (const float*)d_in[0];     // (32,256,32,32)
    const float* emb = (const float*)d_in[1];   // (256,2048)
    float* out = (float*)d_out;
    float* hn = (float*)d_ws;                   // 2048 f32 = 8 KB (proven safe)

    hipLaunchKernelGGL(hn_kernel, dim3(KK / 256), dim3(256), 0, stream, emb, hn);
    hipLaunchKernelGGL(vq_fused, dim3(NN / MT), dim3(512), 0, stream,
                       x, emb, hn, out);
}